// Round 1
// baseline (714.676 us; speedup 1.0000x reference)
//
#include <hip/hip_runtime.h>

#define NN 6144
#define GG 32
#define NPGc 192
#define FINc 32
#define FEc 8
#define Hc 64
#define HMc 128
#define Kc 8
#define Ec 49152
#define NKc (NN*Kc)
#define RTOTc (GG*NPGc*NPGc)

typedef float f32x4 __attribute__((ext_vector_type(4)));
typedef short bf16x8 __attribute__((ext_vector_type(8)));
typedef unsigned long long u64;

__device__ __forceinline__ unsigned short f2bf(float f){
  unsigned u = __float_as_uint(f);
  unsigned r = u + 0x7fffu + ((u>>16)&1u);
  return (unsigned short)(r>>16);
}
__device__ __forceinline__ unsigned fenc(float f){
  unsigned u = __float_as_uint(f);
  return (u & 0x80000000u) ? ~u : (u | 0x80000000u);
}
__device__ __forceinline__ float fdec(unsigned e){
  unsigned u = (e & 0x80000000u) ? (e & 0x7fffffffu) : ~e;
  return __uint_as_float(u);
}
__device__ __forceinline__ void bub8(u64* t8, u64 k){
#pragma unroll
  for (int q=0;q<8;q++){ u64 cur=t8[q]; u64 lo=(k<cur)?k:cur; u64 hi=(k<cur)?cur:k; t8[q]=lo; k=hi; }
}

// ---------------- init: zero accumulators, set x2enc to encode(-inf) ----------------
__global__ void k_init(unsigned* x2enc, float* dbins, float* stats){
  int idx = blockIdx.x*256 + threadIdx.x;
  if (idx < NN*Hc) x2enc[idx] = 0x007FFFFFu;   // fenc(-inf)
  if (idx < 64*256) dbins[idx] = 0.f;
  if (idx < 768) stats[idx] = 0.f;
}

// ---------------- x1a = x @ ef_wroot ----------------
__global__ __launch_bounds__(256) void k_root(const float* __restrict__ x, const float* __restrict__ wr, float* __restrict__ x1a){
  __shared__ float Ws[FINc*Hc];
  __shared__ float xr[4][FINc];
  int t = threadIdx.x;
  for (int q=t;q<FINc*Hc;q+=256) Ws[q] = wr[q];
  int rg = t>>6, j = t&63;
  int r = blockIdx.x*4 + rg;
  if (j < FINc) xr[rg][j] = x[r*FINc + j];
  __syncthreads();
  float a0=0.f, a1=0.f;
#pragma unroll
  for (int k=0;k<FINc;k+=2){
    a0 = fmaf(xr[rg][k],   Ws[k*Hc+j],     a0);
    a1 = fmaf(xr[rg][k+1], Ws[(k+1)*Hc+j], a1);
  }
  x1a[r*Hc + j] = a0 + a1;
}

// ---------------- EdgeFeatsConv messages, atomicAdd into x1a ----------------
__global__ __launch_bounds__(256) void k_edge1(const float* __restrict__ x, const int* __restrict__ ei, const float* __restrict__ ea,
                        const float* __restrict__ w1, const float* __restrict__ b1,
                        const float* __restrict__ w2, const float* __restrict__ b2, float* __restrict__ x1a){
  __shared__ float W1s[72*Hc];
  __shared__ float W2s[Hc*Hc];
  __shared__ float ins[4][80];
  __shared__ float hid[4][Hc];
  int t = threadIdx.x;
  for (int q=t;q<72*Hc;q+=256) W1s[q] = w1[q];
  for (int q=t;q<Hc*Hc;q+=256) W2s[q] = w2[q];
  int eg = t>>6, j = t&63;
  float b1j = b1[j], b2j = b2[j];
  __syncthreads();
  for (int it=0; it<8; it++){
    int e = blockIdx.x*32 + it*4 + eg;
    int s = ei[e], d = ei[Ec + e];
    ins[eg][j] = (j < FINc) ? x[d*FINc + j] : x[s*FINc + (j - FINc)];
    if (j < FEc) ins[eg][64 + j] = ea[e*FEc + j];
    __syncthreads();
    float a0=b1j, a1=0.f, a2=0.f, a3=0.f;
#pragma unroll
    for (int k=0;k<72;k+=4){
      a0 = fmaf(ins[eg][k],   W1s[k*Hc+j],     a0);
      a1 = fmaf(ins[eg][k+1], W1s[(k+1)*Hc+j], a1);
      a2 = fmaf(ins[eg][k+2], W1s[(k+2)*Hc+j], a2);
      a3 = fmaf(ins[eg][k+3], W1s[(k+3)*Hc+j], a3);
    }
    hid[eg][j] = fmaxf((a0+a1)+(a2+a3), 0.f);
    __syncthreads();
    float c0=b2j, c1=0.f, c2=0.f, c3=0.f;
#pragma unroll
    for (int k=0;k<Hc;k+=4){
      c0 = fmaf(hid[eg][k],   W2s[k*Hc+j],     c0);
      c1 = fmaf(hid[eg][k+1], W2s[(k+1)*Hc+j], c1);
      c2 = fmaf(hid[eg][k+2], W2s[(k+2)*Hc+j], c2);
      c3 = fmaf(hid[eg][k+3], W2s[(k+3)*Hc+j], c3);
    }
    atomicAdd(&x1a[d*Hc + j], (c0+c1)+(c2+c3));
    __syncthreads();
  }
}

// ---------------- BN stats over N rows x 64 cols (optionally decoding x2enc) ----------------
__global__ __launch_bounds__(256) void k_bn_stats(const void* __restrict__ src, int isenc, float* __restrict__ gsum, float* __restrict__ gss){
  int t = threadIdx.x;
  int c = t & 63;
  int r0 = blockIdx.x*256 + (t>>6);
  float s=0.f, ss=0.f;
  for (int it=0; it<64; it++){
    int r = r0 + it*4;
    float v;
    if (isenc) v = fdec(((const unsigned*)src)[r*Hc + c]);
    else       v = ((const float*)src)[r*Hc + c];
    s += v; ss += v*v;
  }
  __shared__ float S[64], SS[64];
  if (t < 64){ S[t]=0.f; SS[t]=0.f; }
  __syncthreads();
  atomicAdd(&S[c], s); atomicAdd(&SS[c], ss);
  __syncthreads();
  if (t < 64){ atomicAdd(&gsum[t], S[t]); atomicAdd(&gss[t], SS[t]); }
}

__global__ void k_bn_fin(const float* gsum, const float* gss, const float* gam, const float* bet, float* sc, float* sh){
  int c = threadIdx.x; // 64
  float mean = gsum[c] / (float)NN;
  float var  = gss[c] / (float)NN - mean*mean;
  float rs = rsqrtf(var + 1e-5f);
  float s = rs * gam[c];
  sc[c] = s; sh[c] = bet[c] - mean*s;
}

// ---------------- apply BN1 + per-row squared norm ----------------
__global__ __launch_bounds__(256) void k_apply_bn1_sq(const float* __restrict__ x1a, const float* __restrict__ sc, const float* __restrict__ sh,
                               float* __restrict__ x1bn, float* __restrict__ sqv){
  int t = threadIdx.x;
  int c = t & 63;
  int r = blockIdx.x*4 + (t>>6);
  float v = x1a[r*Hc + c]*sc[c] + sh[c];
  x1bn[r*Hc + c] = v;
  float s = v*v;
#pragma unroll
  for (int off=1; off<64; off<<=1) s += __shfl_xor(s, off, 64);
  if (c == 0) sqv[r] = s;
}

// ---------------- KNN: fused distances + online top-8 per column chunk ----------------
__global__ __launch_bounds__(128,2) void k_knn(const float* __restrict__ x1bn, const float* __restrict__ sqv, u64* __restrict__ parts, int CH){
  __shared__ __align__(16) float XJ[64][68];
  __shared__ float sqj[64];
  int t = threadIdx.x;
  int i1 = blockIdx.x*256 + t;
  int i2 = i1 + 128;
  float4 xa[16], xb[16];
#pragma unroll
  for (int q=0;q<16;q++){
    xa[q] = *(const float4*)(x1bn + i1*Hc + q*4);
    xb[q] = *(const float4*)(x1bn + i2*Hc + q*4);
  }
  float sqi1 = sqv[i1], sqi2 = sqv[i2];
  u64 t8a[8], t8b[8];
#pragma unroll
  for (int q=0;q<8;q++){ t8a[q] = ~0ull; t8b[q] = ~0ull; }
  int cpc = NN / CH;
  int nsub = cpc / 64;
  int jbase0 = blockIdx.y * cpc;
  for (int sub=0; sub<nsub; sub++){
    int jb = jbase0 + sub*64;
    __syncthreads();
    {
      int c = t>>1, hh = t&1;
      const float4* srcp = (const float4*)(x1bn + (jb + c)*Hc + hh*32);
#pragma unroll
      for (int q=0;q<8;q++) *(float4*)&XJ[c][hh*32 + q*4] = srcp[q];
      if (t < 64) sqj[t] = sqv[jb + t];
    }
    __syncthreads();
    for (int j=0;j<64;j++){
      float a0=0,a1=0,a2=0,a3=0,b0=0,b1=0,b2=0,b3=0;
#pragma unroll
      for (int q=0;q<16;q++){
        float4 xj = *(const float4*)&XJ[j][q*4];
        a0=fmaf(xa[q].x,xj.x,a0); a1=fmaf(xa[q].y,xj.y,a1); a2=fmaf(xa[q].z,xj.z,a2); a3=fmaf(xa[q].w,xj.w,a3);
        b0=fmaf(xb[q].x,xj.x,b0); b1=fmaf(xb[q].y,xj.y,b1); b2=fmaf(xb[q].z,xj.z,b2); b3=fmaf(xb[q].w,xj.w,b3);
      }
      float dot1 = (a0+a1)+(a2+a3);
      float dot2 = (b0+b1)+(b2+b3);
      int jj = jb + j;
      float d2a = (sqi1 + sqj[j]) - 2.f*dot1;
      float d2b = (sqi2 + sqj[j]) - 2.f*dot2;
      u64 ka = (((u64)fenc(d2a))<<32) | (unsigned)jj;
      u64 kb = (((u64)fenc(d2b))<<32) | (unsigned)jj;
      if (jj != i1 && ka < t8a[7]) bub8(t8a, ka);
      if (jj != i2 && kb < t8b[7]) bub8(t8b, kb);
    }
  }
  u64* pa = parts + ((size_t)i1*CH + blockIdx.y)*8;
  u64* pb = parts + ((size_t)i2*CH + blockIdx.y)*8;
#pragma unroll
  for (int q=0;q<8;q++){ pa[q] = t8a[q]; pb[q] = t8b[q]; }
}

__global__ __launch_bounds__(256) void k_knn_merge(const u64* __restrict__ parts, int CH, unsigned* __restrict__ nbr){
  int r = blockIdx.x*256 + threadIdx.x;
  u64 t8[8];
#pragma unroll
  for (int q=0;q<8;q++) t8[q] = ~0ull;
  int n = CH*8;
  const u64* p = parts + (size_t)r*CH*8;
  for (int q=0;q<n;q++){
    u64 k = p[q];
    if (k < t8[7]) bub8(t8, k);
  }
#pragma unroll
  for (int s=0;s<8;s++) nbr[r*Kc + s] = (unsigned)(t8[s] & 0xffffffffu);
}

// ---------------- EdgeConv (dynamic graph), atomicMax into encoded x2 ----------------
__global__ __launch_bounds__(256) void k_edge2(const float* __restrict__ x1bn, const unsigned* __restrict__ nbr,
                        const float* __restrict__ w1, const float* __restrict__ b1,
                        const float* __restrict__ w2, const float* __restrict__ b2, unsigned* __restrict__ x2enc){
  __shared__ float W1s[128*Hc];
  __shared__ float W2s[Hc*Hc];
  __shared__ float ins[4][128];
  __shared__ float hid[4][Hc];
  int t = threadIdx.x;
  for (int q=t;q<128*Hc;q+=256) W1s[q] = w1[q];
  for (int q=t;q<Hc*Hc;q+=256) W2s[q] = w2[q];
  int eg = t>>6, j = t&63;
  float b1j = b1[j], b2j = b2[j];
  __syncthreads();
  for (int it=0; it<8; it++){
    int eid = blockIdx.x*32 + it*4 + eg;
    int d, s;
    if (eid < NKc){ d = eid >> 3; s = (int)nbr[eid]; }
    else { int e2 = eid - NKc; s = e2 >> 3; d = (int)nbr[e2]; }
    float vd = x1bn[d*Hc + j];
    float vs = x1bn[s*Hc + j];
    ins[eg][j] = vd;
    ins[eg][64 + j] = vs - vd;
    __syncthreads();
    float a0=b1j, a1=0.f, a2=0.f, a3=0.f;
#pragma unroll
    for (int k=0;k<128;k+=4){
      a0 = fmaf(ins[eg][k],   W1s[k*Hc+j],     a0);
      a1 = fmaf(ins[eg][k+1], W1s[(k+1)*Hc+j], a1);
      a2 = fmaf(ins[eg][k+2], W1s[(k+2)*Hc+j], a2);
      a3 = fmaf(ins[eg][k+3], W1s[(k+3)*Hc+j], a3);
    }
    hid[eg][j] = fmaxf((a0+a1)+(a2+a3), 0.f);
    __syncthreads();
    float c0=b2j, c1=0.f, c2=0.f, c3=0.f;
#pragma unroll
    for (int k=0;k<Hc;k+=4){
      c0 = fmaf(hid[eg][k],   W2s[k*Hc+j],     c0);
      c1 = fmaf(hid[eg][k+1], W2s[(k+1)*Hc+j], c1);
      c2 = fmaf(hid[eg][k+2], W2s[(k+2)*Hc+j], c2);
      c3 = fmaf(hid[eg][k+3], W2s[(k+3)*Hc+j], c3);
    }
    atomicMax(&x2enc[d*Hc + j], fenc((c0+c1)+(c2+c3)));
    __syncthreads();
  }
}

__global__ __launch_bounds__(256) void k_apply_bn2(const unsigned* __restrict__ x2enc, const float* __restrict__ sc, const float* __restrict__ sh, float* __restrict__ x2bn){
  int idx = blockIdx.x*256 + threadIdx.x;
  int c = idx & 63;
  x2bn[idx] = fdec(x2enc[idx])*sc[c] + sh[c];
}

// ---------------- model2 pass 1: column sum/sumsq of diff@W1 via MFMA ----------------
__global__ __launch_bounds__(256,2) void k_d_stats(const float* __restrict__ x2bn, const float* __restrict__ w1, float* __restrict__ dbins){
  __shared__ __align__(16) char sm[24576 + 16384 + 1024];
  unsigned char* A = (unsigned char*)sm;          // 192x64 bf16, row-swizzled
  unsigned char* W = (unsigned char*)sm + 24576;  // W1^T 128x64 bf16, row-swizzled
  float* Ssum = (float*)(sm + 40960);             // 128 sum + 128 sumsq
  int t = threadIdx.x;
  int gid = blockIdx.x; int g = gid / NPGc; int z = gid - g*NPGc;
  const float* xg = x2bn + (size_t)g*NPGc*Hc;
  const float* xz = xg + z*Hc;
  Ssum[t] = 0.f;
#pragma unroll
  for (int q=0;q<8;q++){
    int task = t + 256*q; int c = task & 127; int c4 = task >> 7;
    ushort4 p;
    p.x = f2bf(w1[(4*c4+0)*HMc + c]);
    p.y = f2bf(w1[(4*c4+1)*HMc + c]);
    p.z = f2bf(w1[(4*c4+2)*HMc + c]);
    p.w = f2bf(w1[(4*c4+3)*HMc + c]);
    *(ushort4*)(W + c*128 + ((c4*8) ^ ((c&7)<<4))) = p;
  }
#pragma unroll
  for (int q=0;q<12;q++){
    int task = t + 256*q; int i = task >> 4; int c = task & 15;
    float4 a = *(const float4*)(xg + i*Hc + c*4);
    float4 b = *(const float4*)(xz + c*4);
    ushort4 p;
    p.x = f2bf(fabsf(a.x-b.x)); p.y = f2bf(fabsf(a.y-b.y));
    p.z = f2bf(fabsf(a.z-b.z)); p.w = f2bf(fabsf(a.w-b.w));
    *(ushort4*)(A + i*128 + ((c*8) ^ ((i&7)<<4))) = p;
  }
  __syncthreads();
  int w = t>>6, l = t&63, lr = l&15, lg = l>>4;
  int sw = (lr&7)<<4;
  f32x4 zero = {0.f,0.f,0.f,0.f};
  f32x4 acc[3][8];
#pragma unroll
  for (int r=0;r<3;r++)
#pragma unroll
    for (int c=0;c<8;c++) acc[r][c] = zero;
#pragma unroll
  for (int kk=0;kk<2;kk++){
    bf16x8 af[3], bfr[8];
#pragma unroll
    for (int r=0;r<3;r++){
      int row = (w*3+r)*16 + lr;
      af[r] = *(const bf16x8*)(A + row*128 + ((lg*16 + 64*kk) ^ sw));
    }
#pragma unroll
    for (int c=0;c<8;c++){
      int col = c*16 + lr;
      bfr[c] = *(const bf16x8*)(W + col*128 + ((lg*16 + 64*kk) ^ sw));
    }
#pragma unroll
    for (int r=0;r<3;r++)
#pragma unroll
      for (int c=0;c<8;c++)
        acc[r][c] = __builtin_amdgcn_mfma_f32_16x16x32_bf16(af[r], bfr[c], acc[r][c], 0,0,0);
  }
#pragma unroll
  for (int c=0;c<8;c++){
    int col = c*16 + lr;
    float s=0.f, ss=0.f;
#pragma unroll
    for (int r=0;r<3;r++)
#pragma unroll
      for (int q=0;q<4;q++){ float v = acc[r][c][q]; s += v; ss += v*v; }
    atomicAdd(&Ssum[col], s);
    atomicAdd(&Ssum[128+col], ss);
  }
  __syncthreads();
  if (t < 128){
    int bin = gid & 63;
    atomicAdd(&dbins[bin*256 + t], Ssum[t]);
    atomicAdd(&dbins[bin*256 + 128 + t], Ssum[128+t]);
  }
}

__global__ void k_d_fin(const float* __restrict__ dbins, const float* gam, const float* bet, float* dsc, float* dsh){
  int c = threadIdx.x; // 128
  float s=0.f, ss=0.f;
#pragma unroll 8
  for (int b=0;b<64;b++){ s += dbins[b*256 + c]; ss += dbins[b*256 + 128 + c]; }
  float mean = s / (float)RTOTc;
  float var  = ss / (float)RTOTc - mean*mean;
  float rs = rsqrtf(var + 1e-5f);
  float k = rs * gam[c];
  dsc[c] = k; dsh[c] = bet[c] - mean*k;
}

// ---------------- model2 main: diff@W1 -> BN -> ReLU -> @W2 -> log_softmax ----------------
__global__ __launch_bounds__(256,2) void k_d_main(const float* __restrict__ x2bn, const float* __restrict__ w1,
                         const float* __restrict__ w2, const float* __restrict__ b2g,
                         const float* __restrict__ dsc, const float* __restrict__ dsh, float* __restrict__ out){
  __shared__ __align__(16) char sm[49152 + 4096 + 1024];
  unsigned char* A   = (unsigned char*)sm;           // phase1: A(24K)+W1T(16K); phase2: h2 192x128 bf16 (48K)
  unsigned char* W   = (unsigned char*)sm + 24576;
  unsigned char* W2T = (unsigned char*)sm + 49152;   // 16x128 bf16 (cols>=2 zero)
  float* sS = (float*)(sm + 53248);                  // scale 128 + shift 128
  int t = threadIdx.x;
  int gid = blockIdx.x; int g = gid / NPGc; int z = gid - g*NPGc;
  const float* xg = x2bn + (size_t)g*NPGc*Hc;
  const float* xz = xg + z*Hc;
  if (t < 128){ sS[t] = dsc[t]; sS[128+t] = dsh[t]; }
  {
    int c = t>>4, kc = t&15;
    ushort4 p0 = make_ushort4(0,0,0,0), p1 = make_ushort4(0,0,0,0);
    if (c < 2){
      p0.x = f2bf(w2[(kc*8+0)*2 + c]); p0.y = f2bf(w2[(kc*8+1)*2 + c]);
      p0.z = f2bf(w2[(kc*8+2)*2 + c]); p0.w = f2bf(w2[(kc*8+3)*2 + c]);
      p1.x = f2bf(w2[(kc*8+4)*2 + c]); p1.y = f2bf(w2[(kc*8+5)*2 + c]);
      p1.z = f2bf(w2[(kc*8+6)*2 + c]); p1.w = f2bf(w2[(kc*8+7)*2 + c]);
    }
    int byte = c*256 + ((kc*16) ^ ((c&7)<<4));
    *(ushort4*)(W2T + byte) = p0;
    *(ushort4*)(W2T + byte + 8) = p1;
  }
#pragma unroll
  for (int q=0;q<8;q++){
    int task = t + 256*q; int c = task & 127; int c4 = task >> 7;
    ushort4 p;
    p.x = f2bf(w1[(4*c4+0)*HMc + c]);
    p.y = f2bf(w1[(4*c4+1)*HMc + c]);
    p.z = f2bf(w1[(4*c4+2)*HMc + c]);
    p.w = f2bf(w1[(4*c4+3)*HMc + c]);
    *(ushort4*)(W + c*128 + ((c4*8) ^ ((c&7)<<4))) = p;
  }
#pragma unroll
  for (int q=0;q<12;q++){
    int task = t + 256*q; int i = task >> 4; int c = task & 15;
    float4 a = *(const float4*)(xg + i*Hc + c*4);
    float4 b = *(const float4*)(xz + c*4);
    ushort4 p;
    p.x = f2bf(fabsf(a.x-b.x)); p.y = f2bf(fabsf(a.y-b.y));
    p.z = f2bf(fabsf(a.z-b.z)); p.w = f2bf(fabsf(a.w-b.w));
    *(ushort4*)(A + i*128 + ((c*8) ^ ((i&7)<<4))) = p;
  }
  __syncthreads();
  int w = t>>6, l = t&63, lr = l&15, lg = l>>4;
  int sw = (lr&7)<<4;
  f32x4 zero = {0.f,0.f,0.f,0.f};
  f32x4 acc[3][8];
#pragma unroll
  for (int r=0;r<3;r++)
#pragma unroll
    for (int c=0;c<8;c++) acc[r][c] = zero;
#pragma unroll
  for (int kk=0;kk<2;kk++){
    bf16x8 af[3], bfr[8];
#pragma unroll
    for (int r=0;r<3;r++){
      int row = (w*3+r)*16 + lr;
      af[r] = *(const bf16x8*)(A + row*128 + ((lg*16 + 64*kk) ^ sw));
    }
#pragma unroll
    for (int c=0;c<8;c++){
      int col = c*16 + lr;
      bfr[c] = *(const bf16x8*)(W + col*128 + ((lg*16 + 64*kk) ^ sw));
    }
#pragma unroll
    for (int r=0;r<3;r++)
#pragma unroll
      for (int c=0;c<8;c++)
        acc[r][c] = __builtin_amdgcn_mfma_f32_16x16x32_bf16(af[r], bfr[c], acc[r][c], 0,0,0);
  }
  __syncthreads();   // all MFMA reads of A/W done; reuse as h2
  // BN + ReLU epilogue -> h2 (bf16, row-swizzled [192][128], stride 256B)
#pragma unroll
  for (int r=0;r<3;r++){
#pragma unroll
    for (int c=0;c<8;c++){
      int col = c*16 + lr;
      float scl = sS[col], shf = sS[128+col];
#pragma unroll
      for (int q=0;q<4;q++){
        int row = (w*3+r)*16 + lg*4 + q;
        float v = fmaxf(acc[r][c][q]*scl + shf, 0.f);
        *(unsigned short*)(A + row*256 + ((col*2) ^ ((row&7)<<4))) = f2bf(v);
      }
    }
  }
  __syncthreads();
  // second GEMM: h2 @ W2 (K=128) via MFMA, cols 0..1 valid
  f32x4 acc2[3];
#pragma unroll
  for (int r=0;r<3;r++) acc2[r] = zero;
#pragma unroll
  for (int kk=0;kk<4;kk++){
    bf16x8 bw = *(const bf16x8*)(W2T + lr*256 + ((lg*16 + 64*kk) ^ sw));
#pragma unroll
    for (int r=0;r<3;r++){
      int row = (w*3+r)*16 + lr;
      bf16x8 ah = *(const bf16x8*)(A + row*256 + ((lg*16 + 64*kk) ^ sw));
      acc2[r] = __builtin_amdgcn_mfma_f32_16x16x32_bf16(ah, bw, acc2[r], 0,0,0);
    }
  }
  float b2a = b2g[0], b2b = b2g[1];
  size_t obase = (size_t)gid * NPGc;
#pragma unroll
  for (int r=0;r<3;r++){
#pragma unroll
    for (int q=0;q<4;q++){
      float o = acc2[r][q];
      float oo = __shfl_xor(o, 1, 64);
      if (lr < 2){
        int row = (w*3+r)*16 + lg*4 + q;
        float self = o + ((lr==0) ? b2a : b2b);
        float oth  = oo + ((lr==0) ? b2b : b2a);
        float mx = fmaxf(self, oth);
        float lse = mx + logf(expf(self-mx) + expf(oth-mx));
        out[(obase + row)*2 + lr] = self - lse;
      }
    }
  }
}

extern "C" void kernel_launch(void* const* d_in, const int* in_sizes, int n_in,
                              void* d_out, int out_size, void* d_ws, size_t ws_size,
                              hipStream_t stream){
  const float* x    = (const float*)d_in[0];
  const int*   ei   = (const int*)d_in[1];
  const float* ea   = (const float*)d_in[2];
  const float* efw1 = (const float*)d_in[4];
  const float* efb1 = (const float*)d_in[5];
  const float* efw2 = (const float*)d_in[6];
  const float* efb2 = (const float*)d_in[7];
  const float* efwr = (const float*)d_in[8];
  const float* bn1g = (const float*)d_in[9];
  const float* bn1b = (const float*)d_in[10];
  const float* ecw1 = (const float*)d_in[11];
  const float* ecb1 = (const float*)d_in[12];
  const float* ecw2 = (const float*)d_in[13];
  const float* ecb2 = (const float*)d_in[14];
  const float* bn2g = (const float*)d_in[15];
  const float* bn2b = (const float*)d_in[16];
  const float* m2w1 = (const float*)d_in[17];
  // d_in[18] = m2_b1: cancels exactly in train-mode BN (shift uses batch mean of pre+b1)
  const float* m2bng = (const float*)d_in[19];
  const float* m2bnb = (const float*)d_in[20];
  const float* m2w2  = (const float*)d_in[21];
  const float* m2b2  = (const float*)d_in[22];

  char* ws = (char*)d_ws;
  float*    x1a   = (float*)(ws + 0);
  float*    x1bn  = (float*)(ws + 1572864);
  float*    x2bn  = (float*)(ws + 3145728);
  unsigned* x2enc = (unsigned*)(ws + 4718592);
  float*    sqv   = (float*)(ws + 6291456);
  unsigned* nbr   = (unsigned*)(ws + 6316032);
  float*    stats = (float*)(ws + 6512640);
  float*    dbins = (float*)(ws + 6515712);
  u64*      parts = (u64*)(ws + 6581248);
  float *g1sum = stats,     *g1ss = stats+64,  *sc1 = stats+128, *sh1 = stats+192;
  float *g2sum = stats+256, *g2ss = stats+320, *sc2 = stats+384, *sh2 = stats+448;
  float *dsc = stats+512, *dsh = stats+640;
  float* outp = (float*)d_out;

  int CH = 32;
  if (ws_size < 6581248ull + (size_t)NN*32*64) CH = 16;
  if (ws_size < 6581248ull + (size_t)NN*16*64) CH = 8;

  k_init<<<1536,256,0,stream>>>(x2enc, dbins, stats);
  k_root<<<1536,256,0,stream>>>(x, efwr, x1a);
  k_edge1<<<1536,256,0,stream>>>(x, ei, ea, efw1, efb1, efw2, efb2, x1a);
  k_bn_stats<<<24,256,0,stream>>>(x1a, 0, g1sum, g1ss);
  k_bn_fin<<<1,64,0,stream>>>(g1sum, g1ss, bn1g, bn1b, sc1, sh1);
  k_apply_bn1_sq<<<1536,256,0,stream>>>(x1a, sc1, sh1, x1bn, sqv);
  dim3 kg(24, CH);
  k_knn<<<kg,128,0,stream>>>(x1bn, sqv, parts, CH);
  k_knn_merge<<<24,256,0,stream>>>(parts, CH, nbr);
  k_edge2<<<3072,256,0,stream>>>(x1bn, nbr, ecw1, ecb1, ecw2, ecb2, x2enc);
  k_bn_stats<<<24,256,0,stream>>>(x2enc, 1, g2sum, g2ss);
  k_bn_fin<<<1,64,0,stream>>>(g2sum, g2ss, bn2g, bn2b, sc2, sh2);
  k_apply_bn2<<<1536,256,0,stream>>>(x2enc, sc2, sh2, x2bn);
  k_d_stats<<<6144,256,0,stream>>>(x2bn, m2w1, dbins);
  k_d_fin<<<1,128,0,stream>>>(dbins, m2bng, m2bnb, dsc, dsh);
  k_d_main<<<6144,256,0,stream>>>(x2bn, m2w1, m2w2, m2b2, dsc, dsh, outp);
}

// Round 2
// 705.722 us; speedup vs baseline: 1.0127x; 1.0127x over previous
//
#include <hip/hip_runtime.h>

#define NN 6144
#define GG 32
#define NPGc 192
#define FINc 32
#define FEc 8
#define Hc 64
#define HMc 128
#define Kc 8
#define Ec 49152
#define NKc (NN*Kc)
#define RTOTc (GG*NPGc*NPGc)

typedef float f32x4 __attribute__((ext_vector_type(4)));
typedef short bf16x8 __attribute__((ext_vector_type(8)));
typedef unsigned long long u64;

__device__ __forceinline__ unsigned short f2bf(float f){
  unsigned u = __float_as_uint(f);
  unsigned r = u + 0x7fffu + ((u>>16)&1u);
  return (unsigned short)(r>>16);
}
__device__ __forceinline__ unsigned fenc(float f){
  unsigned u = __float_as_uint(f);
  return (u & 0x80000000u) ? ~u : (u | 0x80000000u);
}
__device__ __forceinline__ float fdec(unsigned e){
  unsigned u = (e & 0x80000000u) ? (e & 0x7fffffffu) : ~e;
  return __uint_as_float(u);
}
__device__ __forceinline__ void bub8(u64* t8, u64 k){
#pragma unroll
  for (int q=0;q<8;q++){ u64 cur=t8[q]; u64 lo=(k<cur)?k:cur; u64 hi=(k<cur)?cur:k; t8[q]=lo; k=hi; }
}

// ---------------- init: zero accumulators, set x2enc to encode(-inf) ----------------
__global__ void k_init(unsigned* x2enc, float* dbins, float* stats){
  int idx = blockIdx.x*256 + threadIdx.x;
  if (idx < NN*Hc) x2enc[idx] = 0x007FFFFFu;   // fenc(-inf)
  if (idx < 64*256) dbins[idx] = 0.f;
  if (idx < 768) stats[idx] = 0.f;
}

// ---------------- x1a = x @ ef_wroot ----------------
__global__ __launch_bounds__(256) void k_root(const float* __restrict__ x, const float* __restrict__ wr, float* __restrict__ x1a){
  __shared__ float Ws[FINc*Hc];
  __shared__ float xr[4][FINc];
  int t = threadIdx.x;
  for (int q=t;q<FINc*Hc;q+=256) Ws[q] = wr[q];
  int rg = t>>6, j = t&63;
  int r = blockIdx.x*4 + rg;
  if (j < FINc) xr[rg][j] = x[r*FINc + j];
  __syncthreads();
  float a0=0.f, a1=0.f;
#pragma unroll
  for (int k=0;k<FINc;k+=2){
    a0 = fmaf(xr[rg][k],   Ws[k*Hc+j],     a0);
    a1 = fmaf(xr[rg][k+1], Ws[(k+1)*Hc+j], a1);
  }
  x1a[r*Hc + j] = a0 + a1;
}

// ---------------- EdgeFeatsConv messages, atomicAdd into x1a ----------------
__global__ __launch_bounds__(256) void k_edge1(const float* __restrict__ x, const int* __restrict__ ei, const float* __restrict__ ea,
                        const float* __restrict__ w1, const float* __restrict__ b1,
                        const float* __restrict__ w2, const float* __restrict__ b2, float* __restrict__ x1a){
  __shared__ float W1s[72*Hc];
  __shared__ float W2s[Hc*Hc];
  __shared__ float ins[4][80];
  __shared__ float hid[4][Hc];
  int t = threadIdx.x;
  for (int q=t;q<72*Hc;q+=256) W1s[q] = w1[q];
  for (int q=t;q<Hc*Hc;q+=256) W2s[q] = w2[q];
  int eg = t>>6, j = t&63;
  float b1j = b1[j], b2j = b2[j];
  __syncthreads();
  for (int it=0; it<8; it++){
    int e = blockIdx.x*32 + it*4 + eg;
    int s = ei[e], d = ei[Ec + e];
    ins[eg][j] = (j < FINc) ? x[d*FINc + j] : x[s*FINc + (j - FINc)];
    if (j < FEc) ins[eg][64 + j] = ea[e*FEc + j];
    __syncthreads();
    float a0=b1j, a1=0.f, a2=0.f, a3=0.f;
#pragma unroll
    for (int k=0;k<72;k+=4){
      a0 = fmaf(ins[eg][k],   W1s[k*Hc+j],     a0);
      a1 = fmaf(ins[eg][k+1], W1s[(k+1)*Hc+j], a1);
      a2 = fmaf(ins[eg][k+2], W1s[(k+2)*Hc+j], a2);
      a3 = fmaf(ins[eg][k+3], W1s[(k+3)*Hc+j], a3);
    }
    hid[eg][j] = fmaxf((a0+a1)+(a2+a3), 0.f);
    __syncthreads();
    float c0=b2j, c1=0.f, c2=0.f, c3=0.f;
#pragma unroll
    for (int k=0;k<Hc;k+=4){
      c0 = fmaf(hid[eg][k],   W2s[k*Hc+j],     c0);
      c1 = fmaf(hid[eg][k+1], W2s[(k+1)*Hc+j], c1);
      c2 = fmaf(hid[eg][k+2], W2s[(k+2)*Hc+j], c2);
      c3 = fmaf(hid[eg][k+3], W2s[(k+3)*Hc+j], c3);
    }
    atomicAdd(&x1a[d*Hc + j], (c0+c1)+(c2+c3));
    __syncthreads();
  }
}

// ---------------- BN stats over N rows x 64 cols (optionally decoding x2enc) ----------------
__global__ __launch_bounds__(256) void k_bn_stats(const void* __restrict__ src, int isenc, float* __restrict__ gsum, float* __restrict__ gss){
  int t = threadIdx.x;
  int c = t & 63;
  int r0 = blockIdx.x*256 + (t>>6);
  float s=0.f, ss=0.f;
  for (int it=0; it<64; it++){
    int r = r0 + it*4;
    float v;
    if (isenc) v = fdec(((const unsigned*)src)[r*Hc + c]);
    else       v = ((const float*)src)[r*Hc + c];
    s += v; ss += v*v;
  }
  __shared__ float S[64], SS[64];
  if (t < 64){ S[t]=0.f; SS[t]=0.f; }
  __syncthreads();
  atomicAdd(&S[c], s); atomicAdd(&SS[c], ss);
  __syncthreads();
  if (t < 64){ atomicAdd(&gsum[t], S[t]); atomicAdd(&gss[t], SS[t]); }
}

__global__ void k_bn_fin(const float* gsum, const float* gss, const float* gam, const float* bet, float* sc, float* sh){
  int c = threadIdx.x; // 64
  float mean = gsum[c] / (float)NN;
  float var  = gss[c] / (float)NN - mean*mean;
  float rs = rsqrtf(var + 1e-5f);
  float s = rs * gam[c];
  sc[c] = s; sh[c] = bet[c] - mean*s;
}

// ---------------- apply BN1 + per-row squared norm ----------------
__global__ __launch_bounds__(256) void k_apply_bn1_sq(const float* __restrict__ x1a, const float* __restrict__ sc, const float* __restrict__ sh,
                               float* __restrict__ x1bn, float* __restrict__ sqv){
  int t = threadIdx.x;
  int c = t & 63;
  int r = blockIdx.x*4 + (t>>6);
  float v = x1a[r*Hc + c]*sc[c] + sh[c];
  x1bn[r*Hc + c] = v;
  float s = v*v;
#pragma unroll
  for (int off=1; off<64; off<<=1) s += __shfl_xor(s, off, 64);
  if (c == 0) sqv[r] = s;
}

// ---------------- KNN: fused distances + online top-8, scalar-broadcast xj (no LDS) ----------------
__global__ __launch_bounds__(128) void k_knn(const float* __restrict__ x1bn, const float* __restrict__ sqv, u64* __restrict__ parts, int CH){
  int t = threadIdx.x;
  int i1 = blockIdx.x*256 + t;
  int i2 = i1 + 128;
  float4 xa[16], xb[16];
#pragma unroll
  for (int q=0;q<16;q++){
    xa[q] = *(const float4*)(x1bn + (size_t)i1*Hc + q*4);
    xb[q] = *(const float4*)(x1bn + (size_t)i2*Hc + q*4);
  }
  float sqi1 = sqv[i1], sqi2 = sqv[i2];
  u64 t8a[8], t8b[8];
#pragma unroll
  for (int q=0;q<8;q++){ t8a[q] = ~0ull; t8b[q] = ~0ull; }
  float thra = __uint_as_float(0x7f800000u);   // +inf; becomes NaN while sentinels remain -> !(d2>thr) stays true
  float thrb = thra;
  int cpc = NN / CH;
  int jbase = blockIdx.y * cpc;
  const float* __restrict__ jp = x1bn + (size_t)jbase * Hc;   // wave-uniform -> scalar loads
  const float* __restrict__ sp = sqv + jbase;
  for (int j = 0; j < cpc; j++){
    float sqjc = sp[j];
    float4 xj[16];
#pragma unroll
    for (int q=0;q<16;q++) xj[q] = *(const float4*)(jp + q*4);
    jp += Hc;
    float a0=0.f,a1=0.f,a2=0.f,a3=0.f,b0=0.f,b1=0.f,b2=0.f,b3=0.f;
#pragma unroll
    for (int q=0;q<16;q++){
      a0=fmaf(xa[q].x,xj[q].x,a0); a1=fmaf(xa[q].y,xj[q].y,a1); a2=fmaf(xa[q].z,xj[q].z,a2); a3=fmaf(xa[q].w,xj[q].w,a3);
      b0=fmaf(xb[q].x,xj[q].x,b0); b1=fmaf(xb[q].y,xj[q].y,b1); b2=fmaf(xb[q].z,xj[q].z,b2); b3=fmaf(xb[q].w,xj[q].w,b3);
    }
    float dot1 = (a0+a1)+(a2+a3);
    float dot2 = (b0+b1)+(b2+b3);
    int jj = jbase + j;
    float d2a = (sqi1 + sqjc) - 2.f*dot1;
    float d2b = (sqi2 + sqjc) - 2.f*dot2;
    bool ia = !(d2a > thra) && (jj != i1);
    bool ib = !(d2b > thrb) && (jj != i2);
    if (__builtin_expect(ia | ib, 0)){
      if (ia){
        u64 ka = (((u64)fenc(d2a))<<32) | (unsigned)jj;
        bub8(t8a, ka);
        thra = fdec((unsigned)(t8a[7]>>32));
      }
      if (ib){
        u64 kb = (((u64)fenc(d2b))<<32) | (unsigned)jj;
        bub8(t8b, kb);
        thrb = fdec((unsigned)(t8b[7]>>32));
      }
    }
  }
  // transposed layout: parts[(chunk*NN + row)*8 + q] -> coalesced writes & merge reads
  u64* pa = parts + ((size_t)blockIdx.y*NN + i1)*8;
  u64* pb = parts + ((size_t)blockIdx.y*NN + i2)*8;
#pragma unroll
  for (int q=0;q<8;q++){ pa[q] = t8a[q]; pb[q] = t8b[q]; }
}

__global__ __launch_bounds__(256) void k_knn_merge(const u64* __restrict__ parts, int CH, unsigned* __restrict__ nbr){
  int r = blockIdx.x*256 + threadIdx.x;
  u64 t8[8];
#pragma unroll
  for (int q=0;q<8;q++) t8[q] = ~0ull;
  for (int ch=0; ch<CH; ch++){
    const u64* p = parts + ((size_t)ch*NN + r)*8;
    u64 k[8];
#pragma unroll
    for (int q=0;q<8;q++) k[q] = p[q];     // coalesced 64B/lane
#pragma unroll
    for (int q=0;q<8;q++){
      if (k[q] >= t8[7]) break;            // parts are sorted ascending
      bub8(t8, k[q]);
    }
  }
#pragma unroll
  for (int s=0;s<8;s++) nbr[r*Kc + s] = (unsigned)(t8[s] & 0xffffffffu);
}

// ---------------- EdgeConv (dynamic graph), atomicMax into encoded x2 ----------------
__global__ __launch_bounds__(256) void k_edge2(const float* __restrict__ x1bn, const unsigned* __restrict__ nbr,
                        const float* __restrict__ w1, const float* __restrict__ b1,
                        const float* __restrict__ w2, const float* __restrict__ b2, unsigned* __restrict__ x2enc){
  __shared__ float W1s[128*Hc];
  __shared__ float W2s[Hc*Hc];
  __shared__ float ins[4][128];
  __shared__ float hid[4][Hc];
  int t = threadIdx.x;
  for (int q=t;q<128*Hc;q+=256) W1s[q] = w1[q];
  for (int q=t;q<Hc*Hc;q+=256) W2s[q] = w2[q];
  int eg = t>>6, j = t&63;
  float b1j = b1[j], b2j = b2[j];
  __syncthreads();
  for (int it=0; it<8; it++){
    int eid = blockIdx.x*32 + it*4 + eg;
    int d, s;
    if (eid < NKc){ d = eid >> 3; s = (int)nbr[eid]; }
    else { int e2 = eid - NKc; s = e2 >> 3; d = (int)nbr[e2]; }
    float vd = x1bn[d*Hc + j];
    float vs = x1bn[s*Hc + j];
    ins[eg][j] = vd;
    ins[eg][64 + j] = vs - vd;
    __syncthreads();
    float a0=b1j, a1=0.f, a2=0.f, a3=0.f;
#pragma unroll
    for (int k=0;k<128;k+=4){
      a0 = fmaf(ins[eg][k],   W1s[k*Hc+j],     a0);
      a1 = fmaf(ins[eg][k+1], W1s[(k+1)*Hc+j], a1);
      a2 = fmaf(ins[eg][k+2], W1s[(k+2)*Hc+j], a2);
      a3 = fmaf(ins[eg][k+3], W1s[(k+3)*Hc+j], a3);
    }
    hid[eg][j] = fmaxf((a0+a1)+(a2+a3), 0.f);
    __syncthreads();
    float c0=b2j, c1=0.f, c2=0.f, c3=0.f;
#pragma unroll
    for (int k=0;k<Hc;k+=4){
      c0 = fmaf(hid[eg][k],   W2s[k*Hc+j],     c0);
      c1 = fmaf(hid[eg][k+1], W2s[(k+1)*Hc+j], c1);
      c2 = fmaf(hid[eg][k+2], W2s[(k+2)*Hc+j], c2);
      c3 = fmaf(hid[eg][k+3], W2s[(k+3)*Hc+j], c3);
    }
    atomicMax(&x2enc[d*Hc + j], fenc((c0+c1)+(c2+c3)));
    __syncthreads();
  }
}

__global__ __launch_bounds__(256) void k_apply_bn2(const unsigned* __restrict__ x2enc, const float* __restrict__ sc, const float* __restrict__ sh, float* __restrict__ x2bn){
  int idx = blockIdx.x*256 + threadIdx.x;
  int c = idx & 63;
  x2bn[idx] = fdec(x2enc[idx])*sc[c] + sh[c];
}

// ---------------- model2 pass 1: column sum/sumsq of diff@W1 via MFMA ----------------
__global__ __launch_bounds__(256,2) void k_d_stats(const float* __restrict__ x2bn, const float* __restrict__ w1, float* __restrict__ dbins){
  __shared__ __align__(16) char sm[24576 + 16384 + 1024];
  unsigned char* A = (unsigned char*)sm;          // 192x64 bf16, row-swizzled
  unsigned char* W = (unsigned char*)sm + 24576;  // W1^T 128x64 bf16, row-swizzled
  float* Ssum = (float*)(sm + 40960);             // 128 sum + 128 sumsq
  int t = threadIdx.x;
  int gid = blockIdx.x; int g = gid / NPGc; int z = gid - g*NPGc;
  const float* xg = x2bn + (size_t)g*NPGc*Hc;
  const float* xz = xg + z*Hc;
  Ssum[t] = 0.f;
#pragma unroll
  for (int q=0;q<8;q++){
    int task = t + 256*q; int c = task & 127; int c4 = task >> 7;
    ushort4 p;
    p.x = f2bf(w1[(4*c4+0)*HMc + c]);
    p.y = f2bf(w1[(4*c4+1)*HMc + c]);
    p.z = f2bf(w1[(4*c4+2)*HMc + c]);
    p.w = f2bf(w1[(4*c4+3)*HMc + c]);
    *(ushort4*)(W + c*128 + ((c4*8) ^ ((c&7)<<4))) = p;
  }
#pragma unroll
  for (int q=0;q<12;q++){
    int task = t + 256*q; int i = task >> 4; int c = task & 15;
    float4 a = *(const float4*)(xg + i*Hc + c*4);
    float4 b = *(const float4*)(xz + c*4);
    ushort4 p;
    p.x = f2bf(fabsf(a.x-b.x)); p.y = f2bf(fabsf(a.y-b.y));
    p.z = f2bf(fabsf(a.z-b.z)); p.w = f2bf(fabsf(a.w-b.w));
    *(ushort4*)(A + i*128 + ((c*8) ^ ((i&7)<<4))) = p;
  }
  __syncthreads();
  int w = t>>6, l = t&63, lr = l&15, lg = l>>4;
  int sw = (lr&7)<<4;
  f32x4 zero = {0.f,0.f,0.f,0.f};
  f32x4 acc[3][8];
#pragma unroll
  for (int r=0;r<3;r++)
#pragma unroll
    for (int c=0;c<8;c++) acc[r][c] = zero;
#pragma unroll
  for (int kk=0;kk<2;kk++){
    bf16x8 af[3], bfr[8];
#pragma unroll
    for (int r=0;r<3;r++){
      int row = (w*3+r)*16 + lr;
      af[r] = *(const bf16x8*)(A + row*128 + ((lg*16 + 64*kk) ^ sw));
    }
#pragma unroll
    for (int c=0;c<8;c++){
      int col = c*16 + lr;
      bfr[c] = *(const bf16x8*)(W + col*128 + ((lg*16 + 64*kk) ^ sw));
    }
#pragma unroll
    for (int r=0;r<3;r++)
#pragma unroll
      for (int c=0;c<8;c++)
        acc[r][c] = __builtin_amdgcn_mfma_f32_16x16x32_bf16(af[r], bfr[c], acc[r][c], 0,0,0);
  }
#pragma unroll
  for (int c=0;c<8;c++){
    int col = c*16 + lr;
    float s=0.f, ss=0.f;
#pragma unroll
    for (int r=0;r<3;r++)
#pragma unroll
      for (int q=0;q<4;q++){ float v = acc[r][c][q]; s += v; ss = fmaf(v,v,ss); }
    // pre-reduce across the 4 lane-groups sharing this col -> 8x fewer LDS atomics
    s  += __shfl_xor(s, 16, 64);  ss += __shfl_xor(ss, 16, 64);
    s  += __shfl_xor(s, 32, 64);  ss += __shfl_xor(ss, 32, 64);
    if (lg == 0){
      atomicAdd(&Ssum[col], s);
      atomicAdd(&Ssum[128+col], ss);
    }
  }
  __syncthreads();
  if (t < 128){
    int bin = gid & 63;
    atomicAdd(&dbins[bin*256 + t], Ssum[t]);
    atomicAdd(&dbins[bin*256 + 128 + t], Ssum[128+t]);
  }
}

__global__ void k_d_fin(const float* __restrict__ dbins, const float* gam, const float* bet, float* dsc, float* dsh){
  int c = threadIdx.x; // 128
  float s=0.f, ss=0.f;
#pragma unroll 8
  for (int b=0;b<64;b++){ s += dbins[b*256 + c]; ss += dbins[b*256 + 128 + c]; }
  float mean = s / (float)RTOTc;
  float var  = ss / (float)RTOTc - mean*mean;
  float rs = rsqrtf(var + 1e-5f);
  float k = rs * gam[c];
  dsc[c] = k; dsh[c] = bet[c] - mean*k;
}

// ---------------- model2 main: diff@W1 -> BN -> ReLU -> @W2 -> log_softmax ----------------
__global__ __launch_bounds__(256,2) void k_d_main(const float* __restrict__ x2bn, const float* __restrict__ w1,
                         const float* __restrict__ w2, const float* __restrict__ b2g,
                         const float* __restrict__ dsc, const float* __restrict__ dsh, float* __restrict__ out){
  __shared__ __align__(16) char sm[49152 + 4096 + 1024];
  unsigned char* A   = (unsigned char*)sm;           // phase1: A(24K)+W1T(16K); phase2: h2 192x128 bf16 (48K)
  unsigned char* W   = (unsigned char*)sm + 24576;
  unsigned char* W2T = (unsigned char*)sm + 49152;   // 16x128 bf16 (cols>=2 zero)
  float* sS = (float*)(sm + 53248);                  // scale 128 + shift 128
  int t = threadIdx.x;
  int gid = blockIdx.x; int g = gid / NPGc; int z = gid - g*NPGc;
  const float* xg = x2bn + (size_t)g*NPGc*Hc;
  const float* xz = xg + z*Hc;
  if (t < 128){ sS[t] = dsc[t]; sS[128+t] = dsh[t]; }
  {
    int c = t>>4, kc = t&15;
    ushort4 p0 = make_ushort4(0,0,0,0), p1 = make_ushort4(0,0,0,0);
    if (c < 2){
      p0.x = f2bf(w2[(kc*8+0)*2 + c]); p0.y = f2bf(w2[(kc*8+1)*2 + c]);
      p0.z = f2bf(w2[(kc*8+2)*2 + c]); p0.w = f2bf(w2[(kc*8+3)*2 + c]);
      p1.x = f2bf(w2[(kc*8+4)*2 + c]); p1.y = f2bf(w2[(kc*8+5)*2 + c]);
      p1.z = f2bf(w2[(kc*8+6)*2 + c]); p1.w = f2bf(w2[(kc*8+7)*2 + c]);
    }
    int byte = c*256 + ((kc*16) ^ ((c&7)<<4));
    *(ushort4*)(W2T + byte) = p0;
    *(ushort4*)(W2T + byte + 8) = p1;
  }
#pragma unroll
  for (int q=0;q<8;q++){
    int task = t + 256*q; int c = task & 127; int c4 = task >> 7;
    ushort4 p;
    p.x = f2bf(w1[(4*c4+0)*HMc + c]);
    p.y = f2bf(w1[(4*c4+1)*HMc + c]);
    p.z = f2bf(w1[(4*c4+2)*HMc + c]);
    p.w = f2bf(w1[(4*c4+3)*HMc + c]);
    *(ushort4*)(W + c*128 + ((c4*8) ^ ((c&7)<<4))) = p;
  }
#pragma unroll
  for (int q=0;q<12;q++){
    int task = t + 256*q; int i = task >> 4; int c = task & 15;
    float4 a = *(const float4*)(xg + i*Hc + c*4);
    float4 b = *(const float4*)(xz + c*4);
    ushort4 p;
    p.x = f2bf(fabsf(a.x-b.x)); p.y = f2bf(fabsf(a.y-b.y));
    p.z = f2bf(fabsf(a.z-b.z)); p.w = f2bf(fabsf(a.w-b.w));
    *(ushort4*)(A + i*128 + ((c*8) ^ ((i&7)<<4))) = p;
  }
  __syncthreads();
  int w = t>>6, l = t&63, lr = l&15, lg = l>>4;
  int sw = (lr&7)<<4;
  f32x4 zero = {0.f,0.f,0.f,0.f};
  f32x4 acc[3][8];
#pragma unroll
  for (int r=0;r<3;r++)
#pragma unroll
    for (int c=0;c<8;c++) acc[r][c] = zero;
#pragma unroll
  for (int kk=0;kk<2;kk++){
    bf16x8 af[3], bfr[8];
#pragma unroll
    for (int r=0;r<3;r++){
      int row = (w*3+r)*16 + lr;
      af[r] = *(const bf16x8*)(A + row*128 + ((lg*16 + 64*kk) ^ sw));
    }
#pragma unroll
    for (int c=0;c<8;c++){
      int col = c*16 + lr;
      bfr[c] = *(const bf16x8*)(W + col*128 + ((lg*16 + 64*kk) ^ sw));
    }
#pragma unroll
    for (int r=0;r<3;r++)
#pragma unroll
      for (int c=0;c<8;c++)
        acc[r][c] = __builtin_amdgcn_mfma_f32_16x16x32_bf16(af[r], bfr[c], acc[r][c], 0,0,0);
  }
  __syncthreads();   // all MFMA reads of A/W done; reuse as h2
  // BN + ReLU epilogue -> h2 (bf16, row-swizzled [192][128], stride 256B)
#pragma unroll
  for (int r=0;r<3;r++){
#pragma unroll
    for (int c=0;c<8;c++){
      int col = c*16 + lr;
      float scl = sS[col], shf = sS[128+col];
#pragma unroll
      for (int q=0;q<4;q++){
        int row = (w*3+r)*16 + lg*4 + q;
        float v = fmaxf(acc[r][c][q]*scl + shf, 0.f);
        *(unsigned short*)(A + row*256 + ((col*2) ^ ((row&7)<<4))) = f2bf(v);
      }
    }
  }
  __syncthreads();
  // second GEMM: h2 @ W2 (K=128) via MFMA, cols 0..1 valid
  f32x4 acc2[3];
#pragma unroll
  for (int r=0;r<3;r++) acc2[r] = zero;
#pragma unroll
  for (int kk=0;kk<4;kk++){
    bf16x8 bw = *(const bf16x8*)(W2T + lr*256 + ((lg*16 + 64*kk) ^ sw));
#pragma unroll
    for (int r=0;r<3;r++){
      int row = (w*3+r)*16 + lr;
      bf16x8 ah = *(const bf16x8*)(A + row*256 + ((lg*16 + 64*kk) ^ sw));
      acc2[r] = __builtin_amdgcn_mfma_f32_16x16x32_bf16(ah, bw, acc2[r], 0,0,0);
    }
  }
  float b2a = b2g[0], b2b = b2g[1];
  size_t obase = (size_t)gid * NPGc;
#pragma unroll
  for (int r=0;r<3;r++){
#pragma unroll
    for (int q=0;q<4;q++){
      float o = acc2[r][q];
      float oo = __shfl_xor(o, 1, 64);
      if (lr < 2){
        int row = (w*3+r)*16 + lg*4 + q;
        float self = o + ((lr==0) ? b2a : b2b);
        float oth  = oo + ((lr==0) ? b2b : b2a);
        float mx = fmaxf(self, oth);
        float lse = mx + logf(expf(self-mx) + expf(oth-mx));
        out[(obase + row)*2 + lr] = self - lse;
      }
    }
  }
}

extern "C" void kernel_launch(void* const* d_in, const int* in_sizes, int n_in,
                              void* d_out, int out_size, void* d_ws, size_t ws_size,
                              hipStream_t stream){
  const float* x    = (const float*)d_in[0];
  const int*   ei   = (const int*)d_in[1];
  const float* ea   = (const float*)d_in[2];
  const float* efw1 = (const float*)d_in[4];
  const float* efb1 = (const float*)d_in[5];
  const float* efw2 = (const float*)d_in[6];
  const float* efb2 = (const float*)d_in[7];
  const float* efwr = (const float*)d_in[8];
  const float* bn1g = (const float*)d_in[9];
  const float* bn1b = (const float*)d_in[10];
  const float* ecw1 = (const float*)d_in[11];
  const float* ecb1 = (const float*)d_in[12];
  const float* ecw2 = (const float*)d_in[13];
  const float* ecb2 = (const float*)d_in[14];
  const float* bn2g = (const float*)d_in[15];
  const float* bn2b = (const float*)d_in[16];
  const float* m2w1 = (const float*)d_in[17];
  // d_in[18] = m2_b1: cancels exactly in train-mode BN (shift uses batch mean of pre+b1)
  const float* m2bng = (const float*)d_in[19];
  const float* m2bnb = (const float*)d_in[20];
  const float* m2w2  = (const float*)d_in[21];
  const float* m2b2  = (const float*)d_in[22];

  char* ws = (char*)d_ws;
  float*    x1a   = (float*)(ws + 0);
  float*    x1bn  = (float*)(ws + 1572864);
  float*    x2bn  = (float*)(ws + 3145728);
  unsigned* x2enc = (unsigned*)(ws + 4718592);
  float*    sqv   = (float*)(ws + 6291456);
  unsigned* nbr   = (unsigned*)(ws + 6316032);
  float*    stats = (float*)(ws + 6512640);
  float*    dbins = (float*)(ws + 6515712);
  u64*      parts = (u64*)(ws + 6581248);
  float *g1sum = stats,     *g1ss = stats+64,  *sc1 = stats+128, *sh1 = stats+192;
  float *g2sum = stats+256, *g2ss = stats+320, *sc2 = stats+384, *sh2 = stats+448;
  float *dsc = stats+512, *dsh = stats+640;
  float* outp = (float*)d_out;

  int CH = 48;
  if (ws_size < 6581248ull + (size_t)NN*48*64) CH = 24;
  if (ws_size < 6581248ull + (size_t)NN*24*64) CH = 12;

  k_init<<<1536,256,0,stream>>>(x2enc, dbins, stats);
  k_root<<<1536,256,0,stream>>>(x, efwr, x1a);
  k_edge1<<<1536,256,0,stream>>>(x, ei, ea, efw1, efb1, efw2, efb2, x1a);
  k_bn_stats<<<24,256,0,stream>>>(x1a, 0, g1sum, g1ss);
  k_bn_fin<<<1,64,0,stream>>>(g1sum, g1ss, bn1g, bn1b, sc1, sh1);
  k_apply_bn1_sq<<<1536,256,0,stream>>>(x1a, sc1, sh1, x1bn, sqv);
  dim3 kg(24, CH);
  k_knn<<<kg,128,0,stream>>>(x1bn, sqv, parts, CH);
  k_knn_merge<<<24,256,0,stream>>>(parts, CH, nbr);
  k_edge2<<<3072,256,0,stream>>>(x1bn, nbr, ecw1, ecb1, ecw2, ecb2, x2enc);
  k_bn_stats<<<24,256,0,stream>>>(x2enc, 1, g2sum, g2ss);
  k_bn_fin<<<1,64,0,stream>>>(g2sum, g2ss, bn2g, bn2b, sc2, sh2);
  k_apply_bn2<<<1536,256,0,stream>>>(x2enc, sc2, sh2, x2bn);
  k_d_stats<<<6144,256,0,stream>>>(x2bn, m2w1, dbins);
  k_d_fin<<<1,128,0,stream>>>(dbins, m2bng, m2bnb, dsc, dsh);
  k_d_main<<<6144,256,0,stream>>>(x2bn, m2w1, m2w2, m2b2, dsc, dsh, outp);
}